// Round 6
// baseline (73.610 us; speedup 1.0000x reference)
//
#include <hip/hip_runtime.h>
#include <hip/hip_bf16.h>
#include <hip/hip_fp8.h>

// FourierResistor: B=8, N=4096, d=128, H=4, fp32 in/out.
// sum-minus-self decomposition:
//   f[k,b,n,d]  = S[k,b,d] - xe[k,b,n,d],  S = sum_n xe
//   inv[b,n,h,d]= (T[b,h,d] - rfe[b,n,h,d]) / N,  T = sum_n rfe
// Pipeline:
//   K1 gemm: x1b = bf16(x @ W_lt^T)              (MFMA, LDS-restaged stores)
//   K2     : PS partials of S0,S1 from x1b
//   finS   : S0,S1
//   K3 gemm: phi8 = fp8e4m3((x1+pos)@W_phi^T+b)  (4 col tiles; fp8 halves traffic —
//            res=min(1,fn-phi) is clipped for ~99.7% of elems, so phi precision is slack)
//   K4     : PT partials of T from x1b,phi8,S
//   finT   : T
//   K5     : fused: comb MLP + LN -> xs(LDS) -> relu(mn@Wf1^T+b1)@Wf2^T+b2 -> out

#define DEV __device__ __forceinline__

typedef __attribute__((ext_vector_type(8))) short bf16x8;
typedef __attribute__((ext_vector_type(4))) float f32x4;

constexpr int Bb = 8, Nn = 4096;
constexpr int BN = Bb * Nn;     // 32768
constexpr int LDP = 136;        // padded LDS pitch in bf16 elems (272 B)
constexpr int P8  = 144;        // byte pitch for fp8 restage (16B-aligned)

union U8 { ushort u[8]; uint4 v; };

static DEV ushort f2bf(float f) {
    __hip_bfloat16 h = __float2bfloat16(f);
    return *reinterpret_cast<unsigned short*>(&h);
}
static DEV float bf2f(ushort u) {
    return __bfloat162float(*reinterpret_cast<const __hip_bfloat16*>(&u));
}
static DEV unsigned char f2fp8(float f) {
    __hip_fp8_e4m3 q(f);
    return q.__x;
}
static DEV float fp82f(unsigned char u) {
    __hip_fp8_e4m3 q;
    q.__x = u;
    return (float)q;
}

// ---------------------------------------------------------------------------
// MFMA GEMM, K=128, tile 64 rows x 128 cols, 256 thr (4 waves x 16 rows).
// MODE 0: x1b  = bf16(x @ Wlt^T)               (f32 in, bf16 out)
// MODE 1: phi8 = fp8((x1+pos)@Wphi^T + b)      (bf16 in, fp8 out, bid.y col tile)
// ---------------------------------------------------------------------------
template <int MODE>
__global__ __launch_bounds__(256) void k_mfma_gemm(
    const void* __restrict__ Xv, const float* __restrict__ W,
    const float* __restrict__ bias, const float* __restrict__ pos,
    ushort* __restrict__ outB, unsigned char* __restrict__ out8)
{
    __shared__ __align__(16) ushort xs[64 * LDP];    // 17 KB
    __shared__ __align__(16) ushort wsl[128 * LDP];  // 34 KB
    const int t = threadIdx.x;
    const int row0 = blockIdx.x * 64;
    const int jt = (MODE == 1) ? blockIdx.y : 0;

    // ---- stage X tile (64 rows x 128) as bf16 ----
    if (MODE == 0) {
        const float* X = (const float*)Xv;
        #pragma unroll
        for (int i = 0; i < 4; ++i) {
            int e = t + i * 256, r = e >> 4, c = (e & 15) * 8;
            const float* p = X + (size_t)(row0 + r) * 128 + c;
            float4 a = *reinterpret_cast<const float4*>(p);
            float4 b = *reinterpret_cast<const float4*>(p + 4);
            U8 u;
            u.u[0] = f2bf(a.x); u.u[1] = f2bf(a.y); u.u[2] = f2bf(a.z); u.u[3] = f2bf(a.w);
            u.u[4] = f2bf(b.x); u.u[5] = f2bf(b.y); u.u[6] = f2bf(b.z); u.u[7] = f2bf(b.w);
            *reinterpret_cast<uint4*>(xs + r * LDP + c) = u.v;
        }
    } else {
        const ushort* X = (const ushort*)Xv;   // x1b
        #pragma unroll
        for (int i = 0; i < 4; ++i) {
            int e = t + i * 256, r = e >> 4, c = (e & 15) * 8;
            U8 u;
            u.v = *reinterpret_cast<const uint4*>(X + (size_t)(row0 + r) * 128 + c);
            int n = (row0 + r) & (Nn - 1);
            const float* q = pos + (size_t)n * 128 + c;
            float4 pa = *reinterpret_cast<const float4*>(q);
            float4 pb = *reinterpret_cast<const float4*>(q + 4);
            u.u[0] = f2bf(bf2f(u.u[0]) + pa.x);
            u.u[1] = f2bf(bf2f(u.u[1]) + pa.y);
            u.u[2] = f2bf(bf2f(u.u[2]) + pa.z);
            u.u[3] = f2bf(bf2f(u.u[3]) + pa.w);
            u.u[4] = f2bf(bf2f(u.u[4]) + pb.x);
            u.u[5] = f2bf(bf2f(u.u[5]) + pb.y);
            u.u[6] = f2bf(bf2f(u.u[6]) + pb.z);
            u.u[7] = f2bf(bf2f(u.u[7]) + pb.w);
            *reinterpret_cast<uint4*>(xs + r * LDP + c) = u.v;
        }
    }
    // ---- stage W col-tile (128 rows x 128) as bf16 ----
    {
        const float* Wt = W + (size_t)jt * 128 * 128;
        #pragma unroll
        for (int i = 0; i < 8; ++i) {
            int e = t + i * 256, r = e >> 4, c = (e & 15) * 8;
            const float* p = Wt + (size_t)r * 128 + c;
            float4 a = *reinterpret_cast<const float4*>(p);
            float4 b = *reinterpret_cast<const float4*>(p + 4);
            U8 u;
            u.u[0] = f2bf(a.x); u.u[1] = f2bf(a.y); u.u[2] = f2bf(a.z); u.u[3] = f2bf(a.w);
            u.u[4] = f2bf(b.x); u.u[5] = f2bf(b.y); u.u[6] = f2bf(b.z); u.u[7] = f2bf(b.w);
            *reinterpret_cast<uint4*>(wsl + r * LDP + c) = u.v;
        }
    }
    __syncthreads();

    const int w = t >> 6, l = t & 63;
    const int lr = l & 15;
    const int lk = (l >> 4) * 8;

    f32x4 acc[8];
    #pragma unroll
    for (int cf = 0; cf < 8; ++cf) acc[cf] = f32x4{0.f, 0.f, 0.f, 0.f};

    #pragma unroll
    for (int ks = 0; ks < 4; ++ks) {
        bf16x8 a = *reinterpret_cast<const bf16x8*>(xs + (w * 16 + lr) * LDP + ks * 32 + lk);
        #pragma unroll
        for (int cf = 0; cf < 8; ++cf) {
            bf16x8 b = *reinterpret_cast<const bf16x8*>(wsl + (cf * 16 + lr) * LDP + ks * 32 + lk);
            acc[cf] = __builtin_amdgcn_mfma_f32_16x16x32_bf16(a, b, acc[cf], 0, 0, 0);
        }
    }

    __syncthreads();  // MFMA reads of xs done; reuse xs as store-staging

    // C/D layout: col=lane&15, row=(lane>>4)*4+reg
    if (MODE == 0) {
        #pragma unroll
        for (int cf = 0; cf < 8; ++cf) {
            int col = cf * 16 + lr;
            #pragma unroll
            for (int reg = 0; reg < 4; ++reg) {
                int rl = w * 16 + (l >> 4) * 4 + reg;
                xs[rl * LDP + col] = f2bf(acc[cf][reg]);
            }
        }
        __syncthreads();
        #pragma unroll
        for (int i = 0; i < 4; ++i) {
            int e = t + i * 256, r = e >> 4, c = (e & 15) * 8;
            uint4 v = *reinterpret_cast<const uint4*>(xs + r * LDP + c);
            *reinterpret_cast<uint4*>(outB + (size_t)(row0 + r) * 128 + c) = v;
        }
    } else {
        unsigned char* x8 = reinterpret_cast<unsigned char*>(xs);
        #pragma unroll
        for (int cf = 0; cf < 8; ++cf) {
            int col = cf * 16 + lr;
            float bv = bias[jt * 128 + col];
            #pragma unroll
            for (int reg = 0; reg < 4; ++reg) {
                int rl = w * 16 + (l >> 4) * 4 + reg;
                x8[rl * P8 + col] = f2fp8(acc[cf][reg] + bv);
            }
        }
        __syncthreads();
        #pragma unroll
        for (int i = 0; i < 2; ++i) {
            int e = t + i * 256, r = e >> 3, c = (e & 7) * 16;
            uint4 v = *reinterpret_cast<const uint4*>(x8 + r * P8 + c);
            *reinterpret_cast<uint4*>(out8 + (size_t)(row0 + r) * 512 + jt * 128 + c) = v;
        }
    }
}

// ---------------------------------------------------------------------------
// K2: PS partials of S0[b,d]=sum_n x1*c, S1[b,d]=sum_n x1*s
// ---------------------------------------------------------------------------
__global__ __launch_bounds__(256) void k_reduceS(
    const ushort* __restrict__ x1b, const float* __restrict__ pos,
    float* __restrict__ PS)
{
    int b = blockIdx.x >> 6, c64 = blockIdx.x & 63;
    int rr = threadIdx.x >> 5, d0 = (threadIdx.x & 31) * 4;
    float a0[4] = {0,0,0,0}, a1[4] = {0,0,0,0};
    #pragma unroll
    for (int i = 0; i < 8; ++i) {
        int n = c64 * 64 + i * 8 + rr;
        size_t r = (size_t)b * Nn + n;
        ushort4 xv = *reinterpret_cast<const ushort4*>(x1b + r * 128 + d0);
        float4 p = *reinterpret_cast<const float4*>(pos + (size_t)n * 128 + d0);
        float x0 = bf2f(xv.x), x1 = bf2f(xv.y), x2 = bf2f(xv.z), x3 = bf2f(xv.w);
        a0[0] += x0 * p.y; a1[0] += x0 * p.x;
        a0[1] += x1 * p.y; a1[1] += x1 * p.x;
        a0[2] += x2 * p.w; a1[2] += x2 * p.z;
        a0[3] += x3 * p.w; a1[3] += x3 * p.z;
    }
    __shared__ float redA[8][128], redB[8][128];
    #pragma unroll
    for (int j = 0; j < 4; ++j) { redA[rr][d0 + j] = a0[j]; redB[rr][d0 + j] = a1[j]; }
    __syncthreads();
    int tt = threadIdx.x;
    float s = 0.f;
    if (tt < 128) {
        #pragma unroll
        for (int k = 0; k < 8; ++k) s += redA[k][tt];
    } else {
        #pragma unroll
        for (int k = 0; k < 8; ++k) s += redB[k][tt - 128];
    }
    PS[(size_t)blockIdx.x * 256 + tt] = s;
}

__global__ __launch_bounds__(256) void k_finS(
    const float* __restrict__ PS, float* __restrict__ S0, float* __restrict__ S1)
{
    int b = blockIdx.x, t = threadIdx.x;
    float s = 0.f;
    #pragma unroll 8
    for (int c = 0; c < 64; ++c) s += PS[(size_t)(b * 64 + c) * 256 + t];
    if (t < 128) S0[b * 128 + t] = s;
    else         S1[b * 128 + (t - 128)] = s;
}

// ---------------------------------------------------------------------------
// K4: PT partials of T[b,h,d] = sum_n rfe
// ---------------------------------------------------------------------------
__global__ __launch_bounds__(256) void k_reduceT(
    const ushort* __restrict__ x1b, const unsigned char* __restrict__ phi8,
    const float* __restrict__ pos, const float* __restrict__ S0,
    const float* __restrict__ S1, float* __restrict__ PT)
{
    int b = blockIdx.x >> 6, c64 = blockIdx.x & 63;
    int rr = threadIdx.x >> 5, d0 = (threadIdx.x & 31) * 4;
    float4 S0v = *reinterpret_cast<const float4*>(S0 + b * 128 + d0);
    float4 S1v = *reinterpret_cast<const float4*>(S1 + b * 128 + d0);
    float S0a[4] = {S0v.x, S0v.y, S0v.z, S0v.w};
    float S1a[4] = {S1v.x, S1v.y, S1v.z, S1v.w};
    float acc[4][4];
    #pragma unroll
    for (int h = 0; h < 4; ++h)
        #pragma unroll
        for (int j = 0; j < 4; ++j) acc[h][j] = 0.f;

    #pragma unroll 2
    for (int i = 0; i < 8; ++i) {
        int n = c64 * 64 + i * 8 + rr;
        size_t r = (size_t)b * Nn + n;
        ushort4 xv4 = *reinterpret_cast<const ushort4*>(x1b + r * 128 + d0);
        float4 p = *reinterpret_cast<const float4*>(pos + (size_t)n * 128 + d0);
        float xv[4] = {bf2f(xv4.x), bf2f(xv4.y), bf2f(xv4.z), bf2f(xv4.w)};
        float cc[4] = {p.y, p.y, p.w, p.w};
        float ss[4] = {p.x, p.x, p.z, p.z};
        float fec[4], fn[4];
        #pragma unroll
        for (int j = 0; j < 4; ++j) {
            float f0 = S0a[j] - xv[j] * cc[j];
            float f1 = xv[j] * ss[j] - S1a[j];
            fn[j] = sqrtf(f0 * f0 + f1 * f1);
            fec[j] = f0 * cc[j] - f1 * ss[j];
        }
        #pragma unroll
        for (int h = 0; h < 4; ++h) {
            uchar4 ph4 = *reinterpret_cast<const uchar4*>(phi8 + r * 512 + h * 128 + d0);
            float ph[4] = {fp82f(ph4.x), fp82f(ph4.y), fp82f(ph4.z), fp82f(ph4.w)};
            #pragma unroll
            for (int j = 0; j < 4; ++j)
                acc[h][j] += fmaxf(0.f, fminf(1.f, fn[j] - ph[j])) * fec[j];
        }
    }
    __shared__ float red[8][512];
    #pragma unroll
    for (int h = 0; h < 4; ++h)
        #pragma unroll
        for (int j = 0; j < 4; ++j) red[rr][h * 128 + d0 + j] = acc[h][j];
    __syncthreads();
    int tt = threadIdx.x;
    #pragma unroll
    for (int q = 0; q < 2; ++q) {
        int idx = tt + q * 256;
        float s = 0.f;
        #pragma unroll
        for (int k = 0; k < 8; ++k) s += red[k][idx];
        PT[(size_t)blockIdx.x * 512 + idx] = s;
    }
}

__global__ __launch_bounds__(256) void k_finT(
    const float* __restrict__ PT, float* __restrict__ T)
{
    int idx = blockIdx.x * 256 + threadIdx.x;   // 0..4095
    int b = idx >> 9, lo = idx & 511;
    float s = 0.f;
    #pragma unroll 8
    for (int c = 0; c < 64; ++c) s += PT[(size_t)b * 32768 + c * 512 + lo];
    T[idx] = s;
}

// ---------------------------------------------------------------------------
// K5: fused comb+LN+FFN.
// Phase 0: wave per row (16 rows/wave): inv -> comb MLP -> m -> LayerNorm,
//          mn (bf16) written straight into xs LDS tile.
// Phase 1: h1 = relu(mn@Wf1^T+b1) (MFMA, back into xs)
// Phase 2: out = h1@Wf2^T + b2    (MFMA, f32 stores)
// ---------------------------------------------------------------------------
__global__ __launch_bounds__(256) void k_comb_ffn(
    const ushort* __restrict__ x1b, const unsigned char* __restrict__ phi8,
    const float* __restrict__ pos, const float* __restrict__ S0,
    const float* __restrict__ S1, const float* __restrict__ T,
    const float* __restrict__ Wc1, const float* __restrict__ bc1,
    const float* __restrict__ Wc2, const float* __restrict__ bc2,
    const float* __restrict__ lng, const float* __restrict__ lnb,
    const float* __restrict__ Wf1, const float* __restrict__ bf1,
    const float* __restrict__ Wf2, const float* __restrict__ bf2,
    float* __restrict__ out)
{
    __shared__ __align__(16) ushort xs[64 * LDP];
    __shared__ __align__(16) ushort wsl[128 * LDP];
    const int t = threadIdx.x;
    const int row0 = blockIdx.x * 64;
    const int w = t >> 6, l = t & 63;

    // stage Wf1 (independent of phase 0 — issue loads early)
    #pragma unroll
    for (int i = 0; i < 8; ++i) {
        int e = t + i * 256, r = e >> 4, c = (e & 15) * 8;
        const float* p = Wf1 + (size_t)r * 128 + c;
        float4 a = *reinterpret_cast<const float4*>(p);
        float4 b = *reinterpret_cast<const float4*>(p + 4);
        U8 u;
        u.u[0] = f2bf(a.x); u.u[1] = f2bf(a.y); u.u[2] = f2bf(a.z); u.u[3] = f2bf(a.w);
        u.u[4] = f2bf(b.x); u.u[5] = f2bf(b.y); u.u[6] = f2bf(b.z); u.u[7] = f2bf(b.w);
        *reinterpret_cast<uint4*>(wsl + r * LDP + c) = u.v;
    }

    // ---- phase 0: comb + LayerNorm, wave per row, 16 rows per wave ----
    {
        const int d0 = 2 * l;
        const float g0 = lng[d0], g1 = lng[d0 + 1];
        const float be0 = lnb[d0], be1 = lnb[d0 + 1];
        const float c20 = Wc2[0], c21 = Wc2[1], c22 = Wc2[2], c23 = Wc2[3];
        const float b2v = bc2[0];
        for (int i = 0; i < 16; ++i) {
            int rl = w * 16 + i;
            int rrow = row0 + rl;
            int b = rrow >> 12;
            int n = rrow & 4095;
            size_t r = (size_t)rrow;

            ushort2 xv2 = *reinterpret_cast<const ushort2*>(x1b + r * 128 + d0);
            float2 p2 = *reinterpret_cast<const float2*>(pos + (size_t)n * 128 + d0);
            float2 s0 = *reinterpret_cast<const float2*>(S0 + b * 128 + d0);
            float2 s1 = *reinterpret_cast<const float2*>(S1 + b * 128 + d0);
            float cc = p2.y, ss = p2.x;
            float xv[2] = {bf2f(xv2.x), bf2f(xv2.y)};
            float S0a[2] = {s0.x, s0.y}, S1a[2] = {s1.x, s1.y};
            float2 Tv[4];
            #pragma unroll
            for (int h = 0; h < 4; ++h)
                Tv[h] = *reinterpret_cast<const float2*>(T + (b * 4 + h) * 128 + d0);
            uchar2 ph2[4];
            #pragma unroll
            for (int h = 0; h < 4; ++h)
                ph2[h] = *reinterpret_cast<const uchar2*>(phi8 + r * 512 + h * 128 + d0);

            float m[2];
            #pragma unroll
            for (int q = 0; q < 2; ++q) {
                float f0 = S0a[q] - xv[q] * cc;
                float f1 = xv[q] * ss - S1a[q];
                float fn = sqrtf(f0 * f0 + f1 * f1);
                float fec = f0 * cc - f1 * ss;
                float inv[4];
                #pragma unroll
                for (int h = 0; h < 4; ++h) {
                    float ph = fp82f(q ? ph2[h].y : ph2[h].x);
                    float res = fmaxf(0.f, fminf(1.f, fn - ph));
                    float tv = q ? Tv[h].y : Tv[h].x;
                    inv[h] = (tv - res * fec) * (1.f / (float)Nn);
                }
                float comb = b2v;
                float wc2a[4] = {c20, c21, c22, c23};
                #pragma unroll
                for (int h = 0; h < 4; ++h) {
                    float u = bc1[h];
                    #pragma unroll
                    for (int h2 = 0; h2 < 4; ++h2) u += Wc1[h * 4 + h2] * inv[h2];
                    comb += fmaxf(u, 0.f) * wc2a[h];
                }
                m[q] = xv[q] + comb;
            }

            float s = m[0] + m[1];
            #pragma unroll
            for (int off = 32; off; off >>= 1) s += __shfl_xor(s, off);
            float mu = s * (1.f / 128.f);
            float e0 = m[0] - mu, e1 = m[1] - mu;
            float v = e0 * e0 + e1 * e1;
            #pragma unroll
            for (int off = 32; off; off >>= 1) v += __shfl_xor(v, off);
            float rstd = rsqrtf(v * (1.f / 128.f) + 1e-6f);
            ushort2 o;
            o.x = f2bf(e0 * rstd * g0 + be0);
            o.y = f2bf(e1 * rstd * g1 + be1);
            *reinterpret_cast<ushort2*>(xs + rl * LDP + d0) = o;
        }
    }
    __syncthreads();

    const int lr = l & 15;
    const int lk = (l >> 4) * 8;

    // ---- phase 1: h1 = relu(mn @ Wf1^T + b1) ----
    f32x4 acc[8];
    #pragma unroll
    for (int cf = 0; cf < 8; ++cf) acc[cf] = f32x4{0.f, 0.f, 0.f, 0.f};
    #pragma unroll
    for (int ks = 0; ks < 4; ++ks) {
        bf16x8 a = *reinterpret_cast<const bf16x8*>(xs + (w * 16 + lr) * LDP + ks * 32 + lk);
        #pragma unroll
        for (int cf = 0; cf < 8; ++cf) {
            bf16x8 b = *reinterpret_cast<const bf16x8*>(wsl + (cf * 16 + lr) * LDP + ks * 32 + lk);
            acc[cf] = __builtin_amdgcn_mfma_f32_16x16x32_bf16(a, b, acc[cf], 0, 0, 0);
        }
    }
    __syncthreads();

    #pragma unroll
    for (int cf = 0; cf < 8; ++cf) {
        int col = cf * 16 + lr;
        float bv = bf1[col];
        #pragma unroll
        for (int reg = 0; reg < 4; ++reg) {
            int rl = w * 16 + (l >> 4) * 4 + reg;
            xs[rl * LDP + col] = f2bf(fmaxf(acc[cf][reg] + bv, 0.f));
        }
    }
    // restage wsl with Wf2
    #pragma unroll
    for (int i = 0; i < 8; ++i) {
        int e = t + i * 256, r = e >> 4, c = (e & 15) * 8;
        const float* p = Wf2 + (size_t)r * 128 + c;
        float4 a = *reinterpret_cast<const float4*>(p);
        float4 b = *reinterpret_cast<const float4*>(p + 4);
        U8 u;
        u.u[0] = f2bf(a.x); u.u[1] = f2bf(a.y); u.u[2] = f2bf(a.z); u.u[3] = f2bf(a.w);
        u.u[4] = f2bf(b.x); u.u[5] = f2bf(b.y); u.u[6] = f2bf(b.z); u.u[7] = f2bf(b.w);
        *reinterpret_cast<uint4*>(wsl + r * LDP + c) = u.v;
    }
    __syncthreads();

    // ---- phase 2: out = h1 @ Wf2^T + b2 ----
    #pragma unroll
    for (int cf = 0; cf < 8; ++cf) acc[cf] = f32x4{0.f, 0.f, 0.f, 0.f};
    #pragma unroll
    for (int ks = 0; ks < 4; ++ks) {
        bf16x8 a = *reinterpret_cast<const bf16x8*>(xs + (w * 16 + lr) * LDP + ks * 32 + lk);
        #pragma unroll
        for (int cf = 0; cf < 8; ++cf) {
            bf16x8 b = *reinterpret_cast<const bf16x8*>(wsl + (cf * 16 + lr) * LDP + ks * 32 + lk);
            acc[cf] = __builtin_amdgcn_mfma_f32_16x16x32_bf16(a, b, acc[cf], 0, 0, 0);
        }
    }
    #pragma unroll
    for (int cf = 0; cf < 8; ++cf) {
        int col = cf * 16 + lr;
        float bv = bf2[col];
        #pragma unroll
        for (int reg = 0; reg < 4; ++reg) {
            int r = row0 + w * 16 + (l >> 4) * 4 + reg;
            out[(size_t)r * 128 + col] = acc[cf][reg] + bv;
        }
    }
}

// ---------------------------------------------------------------------------
extern "C" void kernel_launch(void* const* d_in, const int* in_sizes, int n_in,
                              void* d_out, int out_size, void* d_ws, size_t ws_size,
                              hipStream_t stream)
{
    const float* x    = (const float*)d_in[0];
    const float* pos  = (const float*)d_in[1];
    const float* Wlt  = (const float*)d_in[2];
    const float* Wphi = (const float*)d_in[3];
    const float* bphi = (const float*)d_in[4];
    const float* Wc1  = (const float*)d_in[5];
    const float* bc1  = (const float*)d_in[6];
    const float* Wc2  = (const float*)d_in[7];
    const float* bc2  = (const float*)d_in[8];
    const float* lng  = (const float*)d_in[9];
    const float* lnb  = (const float*)d_in[10];
    const float* Wf1  = (const float*)d_in[11];
    const float* bf1  = (const float*)d_in[12];
    const float* Wf2  = (const float*)d_in[13];
    const float* bf2  = (const float*)d_in[14];

    float* ws = (float*)d_ws;
    ushort* x1b = (ushort*)ws;                     // [BN*128] bf16   8 MB
    float* S0   = ws + 2097152;                    // [1024]
    float* S1   = S0 + 1024;                       // [1024]
    float* T    = S1 + 1024;                       // [4096]
    float* PS   = T + 4096;                        // [512*256]       512 KB
    float* PT   = PS + 131072;                     // [512*512]       1 MB
    unsigned char* phi8 = (unsigned char*)(ws + 2496512);  // [BN*512] fp8  16 MB
    float* out  = (float*)d_out;

    k_mfma_gemm<0><<<dim3(BN / 64), 256, 0, stream>>>(x, Wlt, nullptr, pos, x1b, nullptr);
    k_reduceS<<<dim3(512), 256, 0, stream>>>(x1b, pos, PS);
    k_finS<<<dim3(Bb), 256, 0, stream>>>(PS, S0, S1);
    k_mfma_gemm<1><<<dim3(BN / 64, 4), 256, 0, stream>>>(x1b, Wphi, bphi, pos, nullptr, phi8);
    k_reduceT<<<dim3(512), 256, 0, stream>>>(x1b, phi8, pos, S0, S1, PT);
    k_finT<<<dim3(16), 256, 0, stream>>>(PT, T);
    k_comb_ffn<<<dim3(BN / 64), 256, 0, stream>>>(x1b, phi8, pos, S0, S1, T,
                                                  Wc1, bc1, Wc2, bc2, lng, lnb,
                                                  Wf1, bf1, Wf2, bf2, out);
}

// Round 7
// 72.651 us; speedup vs baseline: 1.0132x; 1.0132x over previous
//
#include <hip/hip_runtime.h>
#include <hip/hip_bf16.h>

// FourierResistor: B=8, N=4096, d=128, H=4, fp32 in/out.
// sum-minus-self decomposition:
//   f[k,b,n,d]  = S[k,b,d] - xe[k,b,n,d],  S = sum_n xe
//   inv[b,n,h,d]= (T[b,h,d] - rfe[b,n,h,d]) / N,  T = sum_n rfe
// Pipeline (6 dispatches):
//   K1 gemm0 : x1b = bf16(x @ W_lt^T) + fused S-partials -> PS (LDS col-reduce)
//   finS     : S0,S1
//   K3 phi   : phi8 = fp8e4m3((x1+pos)@W_phi^T+b), single pass over 4 col tiles
//              (native v_cvt_pk_fp8_f32 encode; res=min(1,fn-phi) is clipped for
//               ~99.7% of elems so fp8 phi precision is slack)
//   K4 redT  : PT partials of T from x1b,phi8,S
//   finT     : T
//   K5       : fused comb MLP + LN -> LDS -> relu(mn@Wf1^T+b1)@Wf2^T+b2 -> out

#define DEV __device__ __forceinline__

typedef __attribute__((ext_vector_type(8))) short bf16x8;
typedef __attribute__((ext_vector_type(4))) float f32x4;

constexpr int Bb = 8, Nn = 4096;
constexpr int BN = Bb * Nn;     // 32768
constexpr int LDP = 136;        // padded LDS pitch in bf16 elems (272 B)
constexpr int P8  = 144;        // byte pitch for fp8 restage (16B-aligned)

union U8 { ushort u[8]; uint4 v; };

static DEV ushort f2bf(float f) {
    __hip_bfloat16 h = __float2bfloat16(f);
    return *reinterpret_cast<unsigned short*>(&h);
}
static DEV float bf2f(ushort u) {
    return __bfloat162float(*reinterpret_cast<const __hip_bfloat16*>(&u));
}
// native gfx950 OCP-e4m3 converts (1 VALU op each)
static DEV unsigned char f2fp8(float f) {
    return (unsigned char)(__builtin_amdgcn_cvt_pk_fp8_f32(f, f, 0u, false) & 0xff);
}
static DEV float fp8lo(unsigned int u, int) ;  // fwd decl unused

// ---------------------------------------------------------------------------
// K1: x1b = bf16(x @ Wlt^T), fused S-partial reduction (no atomics).
// 256 thr, 64 rows x 128 cols tile.
// ---------------------------------------------------------------------------
__global__ __launch_bounds__(256) void k_gemm0(
    const float* __restrict__ X, const float* __restrict__ W,
    const float* __restrict__ pos, ushort* __restrict__ x1b,
    float* __restrict__ PS)
{
    __shared__ __align__(16) ushort xs[64 * LDP];    // 17 KB
    __shared__ __align__(16) ushort wsl[128 * LDP];  // 34 KB
    __shared__ float red[4][2][128];                 // 4 KB
    const int t = threadIdx.x;
    const int row0 = blockIdx.x * 64;

    // stage X tile (f32 -> bf16)
    #pragma unroll
    for (int i = 0; i < 4; ++i) {
        int e = t + i * 256, r = e >> 4, c = (e & 15) * 8;
        const float* p = X + (size_t)(row0 + r) * 128 + c;
        float4 a = *reinterpret_cast<const float4*>(p);
        float4 b = *reinterpret_cast<const float4*>(p + 4);
        U8 u;
        u.u[0] = f2bf(a.x); u.u[1] = f2bf(a.y); u.u[2] = f2bf(a.z); u.u[3] = f2bf(a.w);
        u.u[4] = f2bf(b.x); u.u[5] = f2bf(b.y); u.u[6] = f2bf(b.z); u.u[7] = f2bf(b.w);
        *reinterpret_cast<uint4*>(xs + r * LDP + c) = u.v;
    }
    // stage W (128x128, f32 -> bf16)
    #pragma unroll
    for (int i = 0; i < 8; ++i) {
        int e = t + i * 256, r = e >> 4, c = (e & 15) * 8;
        const float* p = W + (size_t)r * 128 + c;
        float4 a = *reinterpret_cast<const float4*>(p);
        float4 b = *reinterpret_cast<const float4*>(p + 4);
        U8 u;
        u.u[0] = f2bf(a.x); u.u[1] = f2bf(a.y); u.u[2] = f2bf(a.z); u.u[3] = f2bf(a.w);
        u.u[4] = f2bf(b.x); u.u[5] = f2bf(b.y); u.u[6] = f2bf(b.z); u.u[7] = f2bf(b.w);
        *reinterpret_cast<uint4*>(wsl + r * LDP + c) = u.v;
    }
    __syncthreads();

    const int w = t >> 6, l = t & 63;
    const int lr = l & 15;
    const int lk = (l >> 4) * 8;

    f32x4 acc[8];
    #pragma unroll
    for (int cf = 0; cf < 8; ++cf) acc[cf] = f32x4{0.f, 0.f, 0.f, 0.f};
    #pragma unroll
    for (int ks = 0; ks < 4; ++ks) {
        bf16x8 a = *reinterpret_cast<const bf16x8*>(xs + (w * 16 + lr) * LDP + ks * 32 + lk);
        #pragma unroll
        for (int cf = 0; cf < 8; ++cf) {
            bf16x8 b = *reinterpret_cast<const bf16x8*>(wsl + (cf * 16 + lr) * LDP + ks * 32 + lk);
            acc[cf] = __builtin_amdgcn_mfma_f32_16x16x32_bf16(a, b, acc[cf], 0, 0, 0);
        }
    }
    __syncthreads();

    // restage result into xs (bf16); C/D layout: col=lane&15, row=(lane>>4)*4+reg
    #pragma unroll
    for (int cf = 0; cf < 8; ++cf) {
        int col = cf * 16 + lr;
        #pragma unroll
        for (int reg = 0; reg < 4; ++reg) {
            int rl = w * 16 + (l >> 4) * 4 + reg;
            xs[rl * LDP + col] = f2bf(acc[cf][reg]);
        }
    }
    __syncthreads();

    // coalesced 16B stores
    #pragma unroll
    for (int i = 0; i < 4; ++i) {
        int e = t + i * 256, r = e >> 4, c = (e & 15) * 8;
        uint4 v = *reinterpret_cast<const uint4*>(xs + r * LDP + c);
        *reinterpret_cast<uint4*>(x1b + (size_t)(row0 + r) * 128 + c) = v;
    }

    // fused S-partials: column reduce of xs. thread: c2=t&63 (cols 2c2,2c2+1),
    // g=t>>6 (4 groups x 16 rows). pos reads coalesced per row.
    {
        int c2 = t & 63, g = t >> 6;
        float a0e = 0.f, a1e = 0.f, a0o = 0.f, a1o = 0.f;
        #pragma unroll 4
        for (int i = 0; i < 16; ++i) {
            int r = g * 16 + i;
            int n = (row0 + r) & (Nn - 1);
            unsigned int v = *reinterpret_cast<const unsigned int*>(xs + r * LDP + 2 * c2);
            float lo = bf2f((ushort)(v & 0xffff));
            float hi = bf2f((ushort)(v >> 16));
            float2 p = *reinterpret_cast<const float2*>(pos + (size_t)n * 128 + 2 * c2);
            a0e += lo * p.y; a1e += lo * p.x;   // cols 2c2, 2c2+1 share (s,c) pair
            a0o += hi * p.y; a1o += hi * p.x;
        }
        red[g][0][2 * c2] = a0e; red[g][0][2 * c2 + 1] = a0o;
        red[g][1][2 * c2] = a1e; red[g][1][2 * c2 + 1] = a1o;
    }
    __syncthreads();
    {
        int half = t >> 7, col = t & 127;
        float s = red[0][half][col] + red[1][half][col] + red[2][half][col] + red[3][half][col];
        PS[(size_t)blockIdx.x * 256 + t] = s;
    }
}

__global__ __launch_bounds__(256) void k_finS(
    const float* __restrict__ PS, float* __restrict__ S0, float* __restrict__ S1)
{
    int b = blockIdx.x, t = threadIdx.x;
    float s = 0.f;
    #pragma unroll 8
    for (int c = 0; c < 64; ++c) s += PS[(size_t)(b * 64 + c) * 256 + t];
    if (t < 128) S0[b * 128 + t] = s;
    else         S1[b * 128 + (t - 128)] = s;
}

// ---------------------------------------------------------------------------
// K3: phi8 = fp8((x1+pos)@Wphi^T + b), single pass: block stages x once,
// loops 4 col tiles (W restage + MFMA + fp8 encode + coalesced store).
// ---------------------------------------------------------------------------
__global__ __launch_bounds__(256) void k_gemm_phi(
    const ushort* __restrict__ x1b, const float* __restrict__ W,
    const float* __restrict__ bias, const float* __restrict__ pos,
    unsigned char* __restrict__ phi8)
{
    __shared__ __align__(16) ushort xs[64 * LDP];        // 17 KB
    __shared__ __align__(16) ushort wsl[128 * LDP];      // 34 KB
    __shared__ __align__(16) unsigned char p8[64 * P8];  // 9 KB
    const int t = threadIdx.x;
    const int row0 = blockIdx.x * 64;
    const int w = t >> 6, l = t & 63;
    const int lr = l & 15;
    const int lk = (l >> 4) * 8;

    // stage x1b + pos (bf16)
    #pragma unroll
    for (int i = 0; i < 4; ++i) {
        int e = t + i * 256, r = e >> 4, c = (e & 15) * 8;
        U8 u;
        u.v = *reinterpret_cast<const uint4*>(x1b + (size_t)(row0 + r) * 128 + c);
        int n = (row0 + r) & (Nn - 1);
        const float* q = pos + (size_t)n * 128 + c;
        float4 pa = *reinterpret_cast<const float4*>(q);
        float4 pb = *reinterpret_cast<const float4*>(q + 4);
        u.u[0] = f2bf(bf2f(u.u[0]) + pa.x);
        u.u[1] = f2bf(bf2f(u.u[1]) + pa.y);
        u.u[2] = f2bf(bf2f(u.u[2]) + pa.z);
        u.u[3] = f2bf(bf2f(u.u[3]) + pa.w);
        u.u[4] = f2bf(bf2f(u.u[4]) + pb.x);
        u.u[5] = f2bf(bf2f(u.u[5]) + pb.y);
        u.u[6] = f2bf(bf2f(u.u[6]) + pb.z);
        u.u[7] = f2bf(bf2f(u.u[7]) + pb.w);
        *reinterpret_cast<uint4*>(xs + r * LDP + c) = u.v;
    }

    for (int jt = 0; jt < 4; ++jt) {
        __syncthreads();   // wsl free (prev MFMA done); p8 of jt-1 encoded
        {   // stage W col tile jt; store p8 of jt-1 in the same phase
            const float* Wt = W + (size_t)jt * 128 * 128;
            #pragma unroll
            for (int i = 0; i < 8; ++i) {
                int e = t + i * 256, r = e >> 4, c = (e & 15) * 8;
                const float* p = Wt + (size_t)r * 128 + c;
                float4 a = *reinterpret_cast<const float4*>(p);
                float4 b = *reinterpret_cast<const float4*>(p + 4);
                U8 u;
                u.u[0] = f2bf(a.x); u.u[1] = f2bf(a.y); u.u[2] = f2bf(a.z); u.u[3] = f2bf(a.w);
                u.u[4] = f2bf(b.x); u.u[5] = f2bf(b.y); u.u[6] = f2bf(b.z); u.u[7] = f2bf(b.w);
                *reinterpret_cast<uint4*>(wsl + r * LDP + c) = u.v;
            }
            if (jt > 0) {
                #pragma unroll
                for (int i = 0; i < 2; ++i) {
                    int e = t + i * 256, r = e >> 3, c = (e & 7) * 16;
                    uint4 v = *reinterpret_cast<const uint4*>(p8 + r * P8 + c);
                    *reinterpret_cast<uint4*>(phi8 + (size_t)(row0 + r) * 512 + (jt - 1) * 128 + c) = v;
                }
            }
        }
        __syncthreads();

        f32x4 acc[8];
        #pragma unroll
        for (int cf = 0; cf < 8; ++cf) acc[cf] = f32x4{0.f, 0.f, 0.f, 0.f};
        #pragma unroll
        for (int ks = 0; ks < 4; ++ks) {
            bf16x8 a = *reinterpret_cast<const bf16x8*>(xs + (w * 16 + lr) * LDP + ks * 32 + lk);
            #pragma unroll
            for (int cf = 0; cf < 8; ++cf) {
                bf16x8 b = *reinterpret_cast<const bf16x8*>(wsl + (cf * 16 + lr) * LDP + ks * 32 + lk);
                acc[cf] = __builtin_amdgcn_mfma_f32_16x16x32_bf16(a, b, acc[cf], 0, 0, 0);
            }
        }
        // encode fp8 into p8 (native cvt, 1 op per value)
        #pragma unroll
        for (int cf = 0; cf < 8; ++cf) {
            int col = cf * 16 + lr;
            float bv = bias[jt * 128 + col];
            #pragma unroll
            for (int reg = 0; reg < 4; ++reg) {
                int rl = w * 16 + (l >> 4) * 4 + reg;
                p8[rl * P8 + col] = f2fp8(acc[cf][reg] + bv);
            }
        }
    }
    __syncthreads();
    #pragma unroll
    for (int i = 0; i < 2; ++i) {
        int e = t + i * 256, r = e >> 3, c = (e & 7) * 16;
        uint4 v = *reinterpret_cast<const uint4*>(p8 + r * P8 + c);
        *reinterpret_cast<uint4*>(phi8 + (size_t)(row0 + r) * 512 + 3 * 128 + c) = v;
    }
}

// ---------------------------------------------------------------------------
// K4: PT partials of T[b,h,d] = sum_n rfe
// ---------------------------------------------------------------------------
__global__ __launch_bounds__(256) void k_reduceT(
    const ushort* __restrict__ x1b, const unsigned char* __restrict__ phi8,
    const float* __restrict__ pos, const float* __restrict__ S0,
    const float* __restrict__ S1, float* __restrict__ PT)
{
    int b = blockIdx.x >> 6, c64 = blockIdx.x & 63;
    int rr = threadIdx.x >> 5, d0 = (threadIdx.x & 31) * 4;
    float4 S0v = *reinterpret_cast<const float4*>(S0 + b * 128 + d0);
    float4 S1v = *reinterpret_cast<const float4*>(S1 + b * 128 + d0);
    float S0a[4] = {S0v.x, S0v.y, S0v.z, S0v.w};
    float S1a[4] = {S1v.x, S1v.y, S1v.z, S1v.w};
    float acc[4][4];
    #pragma unroll
    for (int h = 0; h < 4; ++h)
        #pragma unroll
        for (int j = 0; j < 4; ++j) acc[h][j] = 0.f;

    #pragma unroll 2
    for (int i = 0; i < 8; ++i) {
        int n = c64 * 64 + i * 8 + rr;
        size_t r = (size_t)b * Nn + n;
        ushort4 xv4 = *reinterpret_cast<const ushort4*>(x1b + r * 128 + d0);
        float4 p = *reinterpret_cast<const float4*>(pos + (size_t)n * 128 + d0);
        float xv[4] = {bf2f(xv4.x), bf2f(xv4.y), bf2f(xv4.z), bf2f(xv4.w)};
        float cc[4] = {p.y, p.y, p.w, p.w};
        float ss[4] = {p.x, p.x, p.z, p.z};
        float fec[4], fn[4];
        #pragma unroll
        for (int j = 0; j < 4; ++j) {
            float f0 = S0a[j] - xv[j] * cc[j];
            float f1 = xv[j] * ss[j] - S1a[j];
            fn[j] = sqrtf(f0 * f0 + f1 * f1);
            fec[j] = f0 * cc[j] - f1 * ss[j];
        }
        #pragma unroll
        for (int h = 0; h < 4; ++h) {
            unsigned int pv = *reinterpret_cast<const unsigned int*>(phi8 + r * 512 + h * 128 + d0);
            float ph0 = __builtin_amdgcn_cvt_f32_fp8(pv, 0);
            float ph1 = __builtin_amdgcn_cvt_f32_fp8(pv, 1);
            float ph2 = __builtin_amdgcn_cvt_f32_fp8(pv, 2);
            float ph3 = __builtin_amdgcn_cvt_f32_fp8(pv, 3);
            acc[h][0] += fmaxf(0.f, fminf(1.f, fn[0] - ph0)) * fec[0];
            acc[h][1] += fmaxf(0.f, fminf(1.f, fn[1] - ph1)) * fec[1];
            acc[h][2] += fmaxf(0.f, fminf(1.f, fn[2] - ph2)) * fec[2];
            acc[h][3] += fmaxf(0.f, fminf(1.f, fn[3] - ph3)) * fec[3];
        }
    }
    __shared__ float red[8][512];
    #pragma unroll
    for (int h = 0; h < 4; ++h)
        #pragma unroll
        for (int j = 0; j < 4; ++j) red[rr][h * 128 + d0 + j] = acc[h][j];
    __syncthreads();
    int tt = threadIdx.x;
    #pragma unroll
    for (int q = 0; q < 2; ++q) {
        int idx = tt + q * 256;
        float s = 0.f;
        #pragma unroll
        for (int k = 0; k < 8; ++k) s += red[k][idx];
        PT[(size_t)blockIdx.x * 512 + idx] = s;
    }
}

__global__ __launch_bounds__(256) void k_finT(
    const float* __restrict__ PT, float* __restrict__ T)
{
    int idx = blockIdx.x * 256 + threadIdx.x;   // 0..4095
    int b = idx >> 9, lo = idx & 511;
    float s = 0.f;
    #pragma unroll 8
    for (int c = 0; c < 64; ++c) s += PT[(size_t)b * 32768 + c * 512 + lo];
    T[idx] = s;
}

// ---------------------------------------------------------------------------
// K5: fused comb+LN+FFN.
// ---------------------------------------------------------------------------
__global__ __launch_bounds__(256) void k_comb_ffn(
    const ushort* __restrict__ x1b, const unsigned char* __restrict__ phi8,
    const float* __restrict__ pos, const float* __restrict__ S0,
    const float* __restrict__ S1, const float* __restrict__ T,
    const float* __restrict__ Wc1, const float* __restrict__ bc1,
    const float* __restrict__ Wc2, const float* __restrict__ bc2,
    const float* __restrict__ lng, const float* __restrict__ lnb,
    const float* __restrict__ Wf1, const float* __restrict__ bf1,
    const float* __restrict__ Wf2, const float* __restrict__ bf2,
    float* __restrict__ out)
{
    __shared__ __align__(16) ushort xs[64 * LDP];
    __shared__ __align__(16) ushort wsl[128 * LDP];
    const int t = threadIdx.x;
    const int row0 = blockIdx.x * 64;
    const int w = t >> 6, l = t & 63;

    // stage Wf1 early
    #pragma unroll
    for (int i = 0; i < 8; ++i) {
        int e = t + i * 256, r = e >> 4, c = (e & 15) * 8;
        const float* p = Wf1 + (size_t)r * 128 + c;
        float4 a = *reinterpret_cast<const float4*>(p);
        float4 b = *reinterpret_cast<const float4*>(p + 4);
        U8 u;
        u.u[0] = f2bf(a.x); u.u[1] = f2bf(a.y); u.u[2] = f2bf(a.z); u.u[3] = f2bf(a.w);
        u.u[4] = f2bf(b.x); u.u[5] = f2bf(b.y); u.u[6] = f2bf(b.z); u.u[7] = f2bf(b.w);
        *reinterpret_cast<uint4*>(wsl + r * LDP + c) = u.v;
    }

    // ---- phase 0: comb + LayerNorm, wave per row, 16 rows per wave ----
    {
        const int d0 = 2 * l;
        const float g0 = lng[d0], g1 = lng[d0 + 1];
        const float be0 = lnb[d0], be1 = lnb[d0 + 1];
        const float c2v[4] = {Wc2[0], Wc2[1], Wc2[2], Wc2[3]};
        const float b2v = bc2[0];
        for (int i = 0; i < 16; ++i) {
            int rl = w * 16 + i;
            int rrow = row0 + rl;
            int b = rrow >> 12;
            int n = rrow & 4095;
            size_t r = (size_t)rrow;

            ushort2 xv2 = *reinterpret_cast<const ushort2*>(x1b + r * 128 + d0);
            float2 p2 = *reinterpret_cast<const float2*>(pos + (size_t)n * 128 + d0);
            float2 s0 = *reinterpret_cast<const float2*>(S0 + b * 128 + d0);
            float2 s1 = *reinterpret_cast<const float2*>(S1 + b * 128 + d0);
            float cc = p2.y, ss = p2.x;
            float xv[2] = {bf2f(xv2.x), bf2f(xv2.y)};
            float S0a[2] = {s0.x, s0.y}, S1a[2] = {s1.x, s1.y};
            float2 Tv[4];
            #pragma unroll
            for (int h = 0; h < 4; ++h)
                Tv[h] = *reinterpret_cast<const float2*>(T + (b * 4 + h) * 128 + d0);
            float phv[4][2];
            #pragma unroll
            for (int h = 0; h < 4; ++h) {
                unsigned int pu = *reinterpret_cast<const ushort*>(phi8 + r * 512 + h * 128 + d0);
                phv[h][0] = __builtin_amdgcn_cvt_f32_fp8(pu, 0);
                phv[h][1] = __builtin_amdgcn_cvt_f32_fp8(pu, 1);
            }

            float m[2];
            #pragma unroll
            for (int q = 0; q < 2; ++q) {
                float f0 = S0a[q] - xv[q] * cc;
                float f1 = xv[q] * ss - S1a[q];
                float fn = sqrtf(f0 * f0 + f1 * f1);
                float fec = f0 * cc - f1 * ss;
                float inv[4];
                #pragma unroll
                for (int h = 0; h < 4; ++h) {
                    float res = fmaxf(0.f, fminf(1.f, fn - phv[h][q]));
                    float tv = q ? Tv[h].y : Tv[h].x;
                    inv[h] = (tv - res * fec) * (1.f / (float)Nn);
                }
                float comb = b2v;
                #pragma unroll
                for (int h = 0; h < 4; ++h) {
                    float u = bc1[h];
                    #pragma unroll
                    for (int h2 = 0; h2 < 4; ++h2) u += Wc1[h * 4 + h2] * inv[h2];
                    comb += fmaxf(u, 0.f) * c2v[h];
                }
                m[q] = xv[q] + comb;
            }

            float s = m[0] + m[1];
            #pragma unroll
            for (int off = 32; off; off >>= 1) s += __shfl_xor(s, off);
            float mu = s * (1.f / 128.f);
            float e0 = m[0] - mu, e1 = m[1] - mu;
            float v = e0 * e0 + e1 * e1;
            #pragma unroll
            for (int off = 32; off; off >>= 1) v += __shfl_xor(v, off);
            float rstd = rsqrtf(v * (1.f / 128.f) + 1e-6f);
            ushort2 o;
            o.x = f2bf(e0 * rstd * g0 + be0);
            o.y = f2bf(e1 * rstd * g1 + be1);
            *reinterpret_cast<ushort2*>(xs + rl * LDP + d0) = o;
        }
    }
    __syncthreads();

    const int lr = l & 15;
    const int lk = (l >> 4) * 8;

    // ---- phase 1: h1 = relu(mn @ Wf1^T + b1) ----
    f32x4 acc[8];
    #pragma unroll
    for (int cf = 0; cf < 8; ++cf) acc[cf] = f32x4{0.f, 0.f, 0.f, 0.f};
    #pragma unroll
    for (int ks = 0; ks < 4; ++ks) {
        bf16x8 a = *reinterpret_cast<const bf16x8*>(xs + (w * 16 + lr) * LDP + ks * 32 + lk);
        #pragma unroll
        for (int cf = 0; cf < 8; ++cf) {
            bf16x8 b = *reinterpret_cast<const bf16x8*>(wsl + (cf * 16 + lr) * LDP + ks * 32 + lk);
            acc[cf] = __builtin_amdgcn_mfma_f32_16x16x32_bf16(a, b, acc[cf], 0, 0, 0);
        }
    }
    __syncthreads();

    #pragma unroll
    for (int cf = 0; cf < 8; ++cf) {
        int col = cf * 16 + lr;
        float bv = bf1[col];
        #pragma unroll
        for (int reg = 0; reg < 4; ++reg) {
            int rl = w * 16 + (l >> 4) * 4 + reg;
            xs[rl * LDP + col] = f2bf(fmaxf(acc[cf][reg] + bv, 0.f));
        }
    }
    // restage wsl with Wf2
    #pragma unroll
    for (int i = 0; i < 8; ++i) {
        int e = t + i * 256, r = e >> 4, c = (e & 15) * 8;
        const float* p = Wf2 + (size_t)r * 128 + c;
        float4 a = *reinterpret_cast<const float4*>(p);
        float4 b = *reinterpret_cast<const float4*>(p + 4);
        U8 u;
        u.u[0] = f2bf(a.x); u.u[1] = f2bf(a.y); u.u[2] = f2bf(a.z); u.u[3] = f2bf(a.w);
        u.u[4] = f2bf(b.x); u.u[5] = f2bf(b.y); u.u[6] = f2bf(b.z); u.u[7] = f2bf(b.w);
        *reinterpret_cast<uint4*>(wsl + r * LDP + c) = u.v;
    }
    __syncthreads();

    // ---- phase 2: out = h1 @ Wf2^T + b2 ----
    #pragma unroll
    for (int cf = 0; cf < 8; ++cf) acc[cf] = f32x4{0.f, 0.f, 0.f, 0.f};
    #pragma unroll
    for (int ks = 0; ks < 4; ++ks) {
        bf16x8 a = *reinterpret_cast<const bf16x8*>(xs + (w * 16 + lr) * LDP + ks * 32 + lk);
        #pragma unroll
        for (int cf = 0; cf < 8; ++cf) {
            bf16x8 b = *reinterpret_cast<const bf16x8*>(wsl + (cf * 16 + lr) * LDP + ks * 32 + lk);
            acc[cf] = __builtin_amdgcn_mfma_f32_16x16x32_bf16(a, b, acc[cf], 0, 0, 0);
        }
    }
    #pragma unroll
    for (int cf = 0; cf < 8; ++cf) {
        int col = cf * 16 + lr;
        float bv = bf2[col];
        #pragma unroll
        for (int reg = 0; reg < 4; ++reg) {
            int r = row0 + w * 16 + (l >> 4) * 4 + reg;
            out[(size_t)r * 128 + col] = acc[cf][reg] + bv;
        }
    }
}

// ---------------------------------------------------------------------------
extern "C" void kernel_launch(void* const* d_in, const int* in_sizes, int n_in,
                              void* d_out, int out_size, void* d_ws, size_t ws_size,
                              hipStream_t stream)
{
    const float* x    = (const float*)d_in[0];
    const float* pos  = (const float*)d_in[1];
    const float* Wlt  = (const float*)d_in[2];
    const float* Wphi = (const float*)d_in[3];
    const float* bphi = (const float*)d_in[4];
    const float* Wc1  = (const float*)d_in[5];
    const float* bc1  = (const float*)d_in[6];
    const float* Wc2  = (const float*)d_in[7];
    const float* bc2  = (const float*)d_in[8];
    const float* lng  = (const float*)d_in[9];
    const float* lnb  = (const float*)d_in[10];
    const float* Wf1  = (const float*)d_in[11];
    const float* bf1  = (const float*)d_in[12];
    const float* Wf2  = (const float*)d_in[13];
    const float* bf2  = (const float*)d_in[14];

    float* ws = (float*)d_ws;
    ushort* x1b = (ushort*)ws;                     // [BN*128] bf16   8 MB
    float* S0   = ws + 2097152;                    // [1024]
    float* S1   = S0 + 1024;                       // [1024]
    float* T    = S1 + 1024;                       // [4096]
    float* PS   = T + 4096;                        // [512*256]       512 KB
    float* PT   = PS + 131072;                     // [512*512]       1 MB
    unsigned char* phi8 = (unsigned char*)(ws + 2496512);  // [BN*512] fp8  16 MB
    float* out  = (float*)d_out;

    k_gemm0<<<dim3(BN / 64), 256, 0, stream>>>(x, Wlt, pos, x1b, PS);
    k_finS<<<dim3(Bb), 256, 0, stream>>>(PS, S0, S1);
    k_gemm_phi<<<dim3(BN / 64), 256, 0, stream>>>(x1b, Wphi, bphi, pos, phi8);
    k_reduceT<<<dim3(512), 256, 0, stream>>>(x1b, phi8, pos, S0, S1, PT);
    k_finT<<<dim3(16), 256, 0, stream>>>(PT, T);
    k_comb_ffn<<<dim3(BN / 64), 256, 0, stream>>>(x1b, phi8, pos, S0, S1, T,
                                                  Wc1, bc1, Wc2, bc2, lng, lnb,
                                                  Wf1, bf1, Wf2, bf2, out);
}

// Round 8
// 70.389 us; speedup vs baseline: 1.0458x; 1.0321x over previous
//
#include <hip/hip_runtime.h>
#include <hip/hip_bf16.h>

// FourierResistor: B=8, N=4096, d=128, H=4, fp32 in/out.
// sum-minus-self decomposition:
//   f[k,b,n,d]  = S[k,b,d] - xe[k,b,n,d],  S = sum_n xe
//   inv[b,n,h,d]= (T[b,h,d] - rfe[b,n,h,d]) / N,  T = sum_n rfe
// Pipeline (5 dispatches):
//   K1 fused : x1b = bf16(x@Wlt^T); S-partials -> PS; then xs += pos and
//              phi8 = fp8e4m3((x1+pos)@Wphi^T+b) over 4 col tiles, all in one
//              kernel (x1 tile stays in LDS; no re-staging dispatch).
//   finS     : S0,S1
//   K3 redT  : PT partials of T from x1b,phi8,S
//   finT     : T
//   K5       : fused comb MLP + LN -> LDS -> relu(mn@Wf1^T+b1)@Wf2^T+b2 -> out

#define DEV __device__ __forceinline__

typedef __attribute__((ext_vector_type(8))) short bf16x8;
typedef __attribute__((ext_vector_type(4))) float f32x4;

constexpr int Bb = 8, Nn = 4096;
constexpr int BN = Bb * Nn;     // 32768
constexpr int LDP = 136;        // padded LDS pitch in bf16 elems (272 B)
constexpr int P8  = 144;        // byte pitch for fp8 restage (16B-aligned)

union U8 { ushort u[8]; uint4 v; };

static DEV ushort f2bf(float f) {
    __hip_bfloat16 h = __float2bfloat16(f);
    return *reinterpret_cast<unsigned short*>(&h);
}
static DEV float bf2f(ushort u) {
    return __bfloat162float(*reinterpret_cast<const __hip_bfloat16*>(&u));
}
// native gfx950 OCP-e4m3 converts (1 VALU op each)
static DEV unsigned char f2fp8(float f) {
    return (unsigned char)(__builtin_amdgcn_cvt_pk_fp8_f32(f, f, 0u, false) & 0xff);
}

// ---------------------------------------------------------------------------
// K1: fused x-GEMM + S-partials + phi-GEMM.
// 256 thr, 64-row tile. LDS: xs 17KB + wsl 34KB + aux 9KB (red/p8 union) = 60KB.
// ---------------------------------------------------------------------------
__global__ __launch_bounds__(256) void k_fused1(
    const float* __restrict__ X, const float* __restrict__ Wlt,
    const float* __restrict__ Wphi, const float* __restrict__ bphi,
    const float* __restrict__ pos, ushort* __restrict__ x1b,
    unsigned char* __restrict__ phi8, float* __restrict__ PS)
{
    __shared__ __align__(16) ushort xs[64 * LDP];        // 17408 B
    __shared__ __align__(16) ushort wsl[128 * LDP];      // 34816 B
    __shared__ __align__(16) unsigned char aux[64 * P8]; // 9216 B (red | p8)
    float (*red)[2][128] = reinterpret_cast<float (*)[2][128]>(aux);
    unsigned char* p8 = aux;

    const int t = threadIdx.x;
    const int row0 = blockIdx.x * 64;
    const int w = t >> 6, l = t & 63;
    const int lr = l & 15;
    const int lk = (l >> 4) * 8;

    // ---- stage X tile (f32 -> bf16) ----
    #pragma unroll
    for (int i = 0; i < 4; ++i) {
        int e = t + i * 256, r = e >> 4, c = (e & 15) * 8;
        const float* p = X + (size_t)(row0 + r) * 128 + c;
        float4 a = *reinterpret_cast<const float4*>(p);
        float4 b = *reinterpret_cast<const float4*>(p + 4);
        U8 u;
        u.u[0] = f2bf(a.x); u.u[1] = f2bf(a.y); u.u[2] = f2bf(a.z); u.u[3] = f2bf(a.w);
        u.u[4] = f2bf(b.x); u.u[5] = f2bf(b.y); u.u[6] = f2bf(b.z); u.u[7] = f2bf(b.w);
        *reinterpret_cast<uint4*>(xs + r * LDP + c) = u.v;
    }
    // ---- stage Wlt (128x128, f32 -> bf16) ----
    #pragma unroll
    for (int i = 0; i < 8; ++i) {
        int e = t + i * 256, r = e >> 4, c = (e & 15) * 8;
        const float* p = Wlt + (size_t)r * 128 + c;
        float4 a = *reinterpret_cast<const float4*>(p);
        float4 b = *reinterpret_cast<const float4*>(p + 4);
        U8 u;
        u.u[0] = f2bf(a.x); u.u[1] = f2bf(a.y); u.u[2] = f2bf(a.z); u.u[3] = f2bf(a.w);
        u.u[4] = f2bf(b.x); u.u[5] = f2bf(b.y); u.u[6] = f2bf(b.z); u.u[7] = f2bf(b.w);
        *reinterpret_cast<uint4*>(wsl + r * LDP + c) = u.v;
    }
    __syncthreads();

    // ---- MFMA: x1 = x @ Wlt^T ----
    {
        f32x4 acc[8];
        #pragma unroll
        for (int cf = 0; cf < 8; ++cf) acc[cf] = f32x4{0.f, 0.f, 0.f, 0.f};
        #pragma unroll
        for (int ks = 0; ks < 4; ++ks) {
            bf16x8 a = *reinterpret_cast<const bf16x8*>(xs + (w * 16 + lr) * LDP + ks * 32 + lk);
            #pragma unroll
            for (int cf = 0; cf < 8; ++cf) {
                bf16x8 b = *reinterpret_cast<const bf16x8*>(wsl + (cf * 16 + lr) * LDP + ks * 32 + lk);
                acc[cf] = __builtin_amdgcn_mfma_f32_16x16x32_bf16(a, b, acc[cf], 0, 0, 0);
            }
        }
        __syncthreads();  // xs reads done

        // restage x1 into xs (bf16); C/D layout: col=lane&15, row=(lane>>4)*4+reg
        #pragma unroll
        for (int cf = 0; cf < 8; ++cf) {
            int col = cf * 16 + lr;
            #pragma unroll
            for (int reg = 0; reg < 4; ++reg) {
                int rl = w * 16 + (l >> 4) * 4 + reg;
                xs[rl * LDP + col] = f2bf(acc[cf][reg]);
            }
        }
    }
    __syncthreads();

    // ---- phase A: store x1b (coalesced) + S-partial column reduce from xs ----
    #pragma unroll
    for (int i = 0; i < 4; ++i) {
        int e = t + i * 256, r = e >> 4, c = (e & 15) * 8;
        uint4 v = *reinterpret_cast<const uint4*>(xs + r * LDP + c);
        *reinterpret_cast<uint4*>(x1b + (size_t)(row0 + r) * 128 + c) = v;
    }
    {
        int c2 = t & 63, g = t >> 6;
        float a0e = 0.f, a1e = 0.f, a0o = 0.f, a1o = 0.f;
        #pragma unroll 4
        for (int i = 0; i < 16; ++i) {
            int r = g * 16 + i;
            int n = (row0 + r) & (Nn - 1);
            unsigned int v = *reinterpret_cast<const unsigned int*>(xs + r * LDP + 2 * c2);
            float lo = bf2f((ushort)(v & 0xffff));
            float hi = bf2f((ushort)(v >> 16));
            float2 p = *reinterpret_cast<const float2*>(pos + (size_t)n * 128 + 2 * c2);
            a0e += lo * p.y; a1e += lo * p.x;   // cols 2c2, 2c2+1 share (s,c)
            a0o += hi * p.y; a1o += hi * p.x;
        }
        red[g][0][2 * c2] = a0e; red[g][0][2 * c2 + 1] = a0o;
        red[g][1][2 * c2] = a1e; red[g][1][2 * c2 + 1] = a1o;
    }
    __syncthreads();

    // ---- phase B: PS write (reads red) + xs += pos (in place) ----
    {
        int half = t >> 7, col = t & 127;
        float s = red[0][half][col] + red[1][half][col] + red[2][half][col] + red[3][half][col];
        PS[(size_t)blockIdx.x * 256 + t] = s;
    }
    #pragma unroll
    for (int i = 0; i < 4; ++i) {
        int e = t + i * 256, r = e >> 4, c = (e & 15) * 8;
        U8 u;
        u.v = *reinterpret_cast<const uint4*>(xs + r * LDP + c);
        int n = (row0 + r) & (Nn - 1);
        const float* q = pos + (size_t)n * 128 + c;
        float4 pa = *reinterpret_cast<const float4*>(q);
        float4 pb = *reinterpret_cast<const float4*>(q + 4);
        u.u[0] = f2bf(bf2f(u.u[0]) + pa.x);
        u.u[1] = f2bf(bf2f(u.u[1]) + pa.y);
        u.u[2] = f2bf(bf2f(u.u[2]) + pa.z);
        u.u[3] = f2bf(bf2f(u.u[3]) + pa.w);
        u.u[4] = f2bf(bf2f(u.u[4]) + pb.x);
        u.u[5] = f2bf(bf2f(u.u[5]) + pb.y);
        u.u[6] = f2bf(bf2f(u.u[6]) + pb.z);
        u.u[7] = f2bf(bf2f(u.u[7]) + pb.w);
        *reinterpret_cast<uint4*>(xs + r * LDP + c) = u.v;
    }

    // ---- phi loop: 4 col tiles of Wphi; p8 aliases red (red is dead) ----
    for (int jt = 0; jt < 4; ++jt) {
        __syncthreads();   // wsl free / p8 of jt-1 encoded / phase B done
        {
            const float* Wt = Wphi + (size_t)jt * 128 * 128;
            #pragma unroll
            for (int i = 0; i < 8; ++i) {
                int e = t + i * 256, r = e >> 4, c = (e & 15) * 8;
                const float* p = Wt + (size_t)r * 128 + c;
                float4 a = *reinterpret_cast<const float4*>(p);
                float4 b = *reinterpret_cast<const float4*>(p + 4);
                U8 u;
                u.u[0] = f2bf(a.x); u.u[1] = f2bf(a.y); u.u[2] = f2bf(a.z); u.u[3] = f2bf(a.w);
                u.u[4] = f2bf(b.x); u.u[5] = f2bf(b.y); u.u[6] = f2bf(b.z); u.u[7] = f2bf(b.w);
                *reinterpret_cast<uint4*>(wsl + r * LDP + c) = u.v;
            }
            if (jt > 0) {
                #pragma unroll
                for (int i = 0; i < 2; ++i) {
                    int e = t + i * 256, r = e >> 3, c = (e & 7) * 16;
                    uint4 v = *reinterpret_cast<const uint4*>(p8 + r * P8 + c);
                    *reinterpret_cast<uint4*>(phi8 + (size_t)(row0 + r) * 512 + (jt - 1) * 128 + c) = v;
                }
            }
        }
        __syncthreads();

        f32x4 acc[8];
        #pragma unroll
        for (int cf = 0; cf < 8; ++cf) acc[cf] = f32x4{0.f, 0.f, 0.f, 0.f};
        #pragma unroll
        for (int ks = 0; ks < 4; ++ks) {
            bf16x8 a = *reinterpret_cast<const bf16x8*>(xs + (w * 16 + lr) * LDP + ks * 32 + lk);
            #pragma unroll
            for (int cf = 0; cf < 8; ++cf) {
                bf16x8 b = *reinterpret_cast<const bf16x8*>(wsl + (cf * 16 + lr) * LDP + ks * 32 + lk);
                acc[cf] = __builtin_amdgcn_mfma_f32_16x16x32_bf16(a, b, acc[cf], 0, 0, 0);
            }
        }
        #pragma unroll
        for (int cf = 0; cf < 8; ++cf) {
            int col = cf * 16 + lr;
            float bv = bphi[jt * 128 + col];
            #pragma unroll
            for (int reg = 0; reg < 4; ++reg) {
                int rl = w * 16 + (l >> 4) * 4 + reg;
                p8[rl * P8 + col] = f2fp8(acc[cf][reg] + bv);
            }
        }
    }
    __syncthreads();
    #pragma unroll
    for (int i = 0; i < 2; ++i) {
        int e = t + i * 256, r = e >> 3, c = (e & 7) * 16;
        uint4 v = *reinterpret_cast<const uint4*>(p8 + r * P8 + c);
        *reinterpret_cast<uint4*>(phi8 + (size_t)(row0 + r) * 512 + 3 * 128 + c) = v;
    }
}

__global__ __launch_bounds__(256) void k_finS(
    const float* __restrict__ PS, float* __restrict__ S0, float* __restrict__ S1)
{
    int b = blockIdx.x, t = threadIdx.x;
    float s = 0.f;
    #pragma unroll 8
    for (int c = 0; c < 64; ++c) s += PS[(size_t)(b * 64 + c) * 256 + t];
    if (t < 128) S0[b * 128 + t] = s;
    else         S1[b * 128 + (t - 128)] = s;
}

// ---------------------------------------------------------------------------
// K3: PT partials of T[b,h,d] = sum_n rfe
// ---------------------------------------------------------------------------
__global__ __launch_bounds__(256) void k_reduceT(
    const ushort* __restrict__ x1b, const unsigned char* __restrict__ phi8,
    const float* __restrict__ pos, const float* __restrict__ S0,
    const float* __restrict__ S1, float* __restrict__ PT)
{
    int b = blockIdx.x >> 6, c64 = blockIdx.x & 63;
    int rr = threadIdx.x >> 5, d0 = (threadIdx.x & 31) * 4;
    float4 S0v = *reinterpret_cast<const float4*>(S0 + b * 128 + d0);
    float4 S1v = *reinterpret_cast<const float4*>(S1 + b * 128 + d0);
    float S0a[4] = {S0v.x, S0v.y, S0v.z, S0v.w};
    float S1a[4] = {S1v.x, S1v.y, S1v.z, S1v.w};
    float acc[4][4];
    #pragma unroll
    for (int h = 0; h < 4; ++h)
        #pragma unroll
        for (int j = 0; j < 4; ++j) acc[h][j] = 0.f;

    #pragma unroll 2
    for (int i = 0; i < 8; ++i) {
        int n = c64 * 64 + i * 8 + rr;
        size_t r = (size_t)b * Nn + n;
        ushort4 xv4 = *reinterpret_cast<const ushort4*>(x1b + r * 128 + d0);
        float4 p = *reinterpret_cast<const float4*>(pos + (size_t)n * 128 + d0);
        float xv[4] = {bf2f(xv4.x), bf2f(xv4.y), bf2f(xv4.z), bf2f(xv4.w)};
        float cc[4] = {p.y, p.y, p.w, p.w};
        float ss[4] = {p.x, p.x, p.z, p.z};
        float fec[4], fn[4];
        #pragma unroll
        for (int j = 0; j < 4; ++j) {
            float f0 = S0a[j] - xv[j] * cc[j];
            float f1 = xv[j] * ss[j] - S1a[j];
            fn[j] = sqrtf(f0 * f0 + f1 * f1);
            fec[j] = f0 * cc[j] - f1 * ss[j];
        }
        #pragma unroll
        for (int h = 0; h < 4; ++h) {
            unsigned int pv = *reinterpret_cast<const unsigned int*>(phi8 + r * 512 + h * 128 + d0);
            float ph0 = __builtin_amdgcn_cvt_f32_fp8(pv, 0);
            float ph1 = __builtin_amdgcn_cvt_f32_fp8(pv, 1);
            float ph2 = __builtin_amdgcn_cvt_f32_fp8(pv, 2);
            float ph3 = __builtin_amdgcn_cvt_f32_fp8(pv, 3);
            acc[h][0] += fmaxf(0.f, fminf(1.f, fn[0] - ph0)) * fec[0];
            acc[h][1] += fmaxf(0.f, fminf(1.f, fn[1] - ph1)) * fec[1];
            acc[h][2] += fmaxf(0.f, fminf(1.f, fn[2] - ph2)) * fec[2];
            acc[h][3] += fmaxf(0.f, fminf(1.f, fn[3] - ph3)) * fec[3];
        }
    }
    __shared__ float red[8][512];
    #pragma unroll
    for (int h = 0; h < 4; ++h)
        #pragma unroll
        for (int j = 0; j < 4; ++j) red[rr][h * 128 + d0 + j] = acc[h][j];
    __syncthreads();
    int tt = threadIdx.x;
    #pragma unroll
    for (int q = 0; q < 2; ++q) {
        int idx = tt + q * 256;
        float s = 0.f;
        #pragma unroll
        for (int k = 0; k < 8; ++k) s += red[k][idx];
        PT[(size_t)blockIdx.x * 512 + idx] = s;
    }
}

__global__ __launch_bounds__(256) void k_finT(
    const float* __restrict__ PT, float* __restrict__ T)
{
    int idx = blockIdx.x * 256 + threadIdx.x;   // 0..4095
    int b = idx >> 9, lo = idx & 511;
    float s = 0.f;
    #pragma unroll 8
    for (int c = 0; c < 64; ++c) s += PT[(size_t)b * 32768 + c * 512 + lo];
    T[idx] = s;
}

// ---------------------------------------------------------------------------
// K5: fused comb+LN+FFN.
// ---------------------------------------------------------------------------
__global__ __launch_bounds__(256) void k_comb_ffn(
    const ushort* __restrict__ x1b, const unsigned char* __restrict__ phi8,
    const float* __restrict__ pos, const float* __restrict__ S0,
    const float* __restrict__ S1, const float* __restrict__ T,
    const float* __restrict__ Wc1, const float* __restrict__ bc1,
    const float* __restrict__ Wc2, const float* __restrict__ bc2,
    const float* __restrict__ lng, const float* __restrict__ lnb,
    const float* __restrict__ Wf1, const float* __restrict__ bf1,
    const float* __restrict__ Wf2, const float* __restrict__ bf2,
    float* __restrict__ out)
{
    __shared__ __align__(16) ushort xs[64 * LDP];
    __shared__ __align__(16) ushort wsl[128 * LDP];
    const int t = threadIdx.x;
    const int row0 = blockIdx.x * 64;
    const int w = t >> 6, l = t & 63;

    // stage Wf1 early
    #pragma unroll
    for (int i = 0; i < 8; ++i) {
        int e = t + i * 256, r = e >> 4, c = (e & 15) * 8;
        const float* p = Wf1 + (size_t)r * 128 + c;
        float4 a = *reinterpret_cast<const float4*>(p);
        float4 b = *reinterpret_cast<const float4*>(p + 4);
        U8 u;
        u.u[0] = f2bf(a.x); u.u[1] = f2bf(a.y); u.u[2] = f2bf(a.z); u.u[3] = f2bf(a.w);
        u.u[4] = f2bf(b.x); u.u[5] = f2bf(b.y); u.u[6] = f2bf(b.z); u.u[7] = f2bf(b.w);
        *reinterpret_cast<uint4*>(wsl + r * LDP + c) = u.v;
    }

    // ---- phase 0: comb + LayerNorm, wave per row, 16 rows per wave ----
    {
        const int d0 = 2 * l;
        const float g0 = lng[d0], g1 = lng[d0 + 1];
        const float be0 = lnb[d0], be1 = lnb[d0 + 1];
        const float c2v[4] = {Wc2[0], Wc2[1], Wc2[2], Wc2[3]};
        const float b2v = bc2[0];
        for (int i = 0; i < 16; ++i) {
            int rl = w * 16 + i;
            int rrow = row0 + rl;
            int b = rrow >> 12;
            int n = rrow & 4095;
            size_t r = (size_t)rrow;

            ushort2 xv2 = *reinterpret_cast<const ushort2*>(x1b + r * 128 + d0);
            float2 p2 = *reinterpret_cast<const float2*>(pos + (size_t)n * 128 + d0);
            float2 s0 = *reinterpret_cast<const float2*>(S0 + b * 128 + d0);
            float2 s1 = *reinterpret_cast<const float2*>(S1 + b * 128 + d0);
            float cc = p2.y, ss = p2.x;
            float xv[2] = {bf2f(xv2.x), bf2f(xv2.y)};
            float S0a[2] = {s0.x, s0.y}, S1a[2] = {s1.x, s1.y};
            float2 Tv[4];
            #pragma unroll
            for (int h = 0; h < 4; ++h)
                Tv[h] = *reinterpret_cast<const float2*>(T + (b * 4 + h) * 128 + d0);
            float phv[4][2];
            #pragma unroll
            for (int h = 0; h < 4; ++h) {
                unsigned int pu = *reinterpret_cast<const ushort*>(phi8 + r * 512 + h * 128 + d0);
                phv[h][0] = __builtin_amdgcn_cvt_f32_fp8(pu, 0);
                phv[h][1] = __builtin_amdgcn_cvt_f32_fp8(pu, 1);
            }

            float m[2];
            #pragma unroll
            for (int q = 0; q < 2; ++q) {
                float f0 = S0a[q] - xv[q] * cc;
                float f1 = xv[q] * ss - S1a[q];
                float fn = sqrtf(f0 * f0 + f1 * f1);
                float fec = f0 * cc - f1 * ss;
                float inv[4];
                #pragma unroll
                for (int h = 0; h < 4; ++h) {
                    float res = fmaxf(0.f, fminf(1.f, fn - phv[h][q]));
                    float tv = q ? Tv[h].y : Tv[h].x;
                    inv[h] = (tv - res * fec) * (1.f / (float)Nn);
                }
                float comb = b2v;
                #pragma unroll
                for (int h = 0; h < 4; ++h) {
                    float u = bc1[h];
                    #pragma unroll
                    for (int h2 = 0; h2 < 4; ++h2) u += Wc1[h * 4 + h2] * inv[h2];
                    comb += fmaxf(u, 0.f) * c2v[h];
                }
                m[q] = xv[q] + comb;
            }

            float s = m[0] + m[1];
            #pragma unroll
            for (int off = 32; off; off >>= 1) s += __shfl_xor(s, off);
            float mu = s * (1.f / 128.f);
            float e0 = m[0] - mu, e1 = m[1] - mu;
            float v = e0 * e0 + e1 * e1;
            #pragma unroll
            for (int off = 32; off; off >>= 1) v += __shfl_xor(v, off);
            float rstd = rsqrtf(v * (1.f / 128.f) + 1e-6f);
            ushort2 o;
            o.x = f2bf(e0 * rstd * g0 + be0);
            o.y = f2bf(e1 * rstd * g1 + be1);
            *reinterpret_cast<ushort2*>(xs + rl * LDP + d0) = o;
        }
    }
    __syncthreads();

    const int lr = l & 15;
    const int lk = (l >> 4) * 8;

    // ---- phase 1: h1 = relu(mn @ Wf1^T + b1) ----
    f32x4 acc[8];
    #pragma unroll
    for (int cf = 0; cf < 8; ++cf) acc[cf] = f32x4{0.f, 0.f, 0.f, 0.f};
    #pragma unroll
    for (int ks = 0; ks < 4; ++ks) {
        bf16x8 a = *reinterpret_cast<const bf16x8*>(xs + (w * 16 + lr) * LDP + ks * 32 + lk);
        #pragma unroll
        for (int cf = 0; cf < 8; ++cf) {
            bf16x8 b = *reinterpret_cast<const bf16x8*>(wsl + (cf * 16 + lr) * LDP + ks * 32 + lk);
            acc[cf] = __builtin_amdgcn_mfma_f32_16x16x32_bf16(a, b, acc[cf], 0, 0, 0);
        }
    }
    __syncthreads();

    #pragma unroll
    for (int cf = 0; cf < 8; ++cf) {
        int col = cf * 16 + lr;
        float bv = bf1[col];
        #pragma unroll
        for (int reg = 0; reg < 4; ++reg) {
            int rl = w * 16 + (l >> 4) * 4 + reg;
            xs[rl * LDP + col] = f2bf(fmaxf(acc[cf][reg] + bv, 0.f));
        }
    }
    // restage wsl with Wf2
    #pragma unroll
    for (int i = 0; i < 8; ++i) {
        int e = t + i * 256, r = e >> 4, c = (e & 15) * 8;
        const float* p = Wf2 + (size_t)r * 128 + c;
        float4 a = *reinterpret_cast<const float4*>(p);
        float4 b = *reinterpret_cast<const float4*>(p + 4);
        U8 u;
        u.u[0] = f2bf(a.x); u.u[1] = f2bf(a.y); u.u[2] = f2bf(a.z); u.u[3] = f2bf(a.w);
        u.u[4] = f2bf(b.x); u.u[5] = f2bf(b.y); u.u[6] = f2bf(b.z); u.u[7] = f2bf(b.w);
        *reinterpret_cast<uint4*>(wsl + r * LDP + c) = u.v;
    }
    __syncthreads();

    // ---- phase 2: out = h1 @ Wf2^T + b2 ----
    #pragma unroll
    for (int cf = 0; cf < 8; ++cf) acc[cf] = f32x4{0.f, 0.f, 0.f, 0.f};
    #pragma unroll
    for (int ks = 0; ks < 4; ++ks) {
        bf16x8 a = *reinterpret_cast<const bf16x8*>(xs + (w * 16 + lr) * LDP + ks * 32 + lk);
        #pragma unroll
        for (int cf = 0; cf < 8; ++cf) {
            bf16x8 b = *reinterpret_cast<const bf16x8*>(wsl + (cf * 16 + lr) * LDP + ks * 32 + lk);
            acc[cf] = __builtin_amdgcn_mfma_f32_16x16x32_bf16(a, b, acc[cf], 0, 0, 0);
        }
    }
    #pragma unroll
    for (int cf = 0; cf < 8; ++cf) {
        int col = cf * 16 + lr;
        float bv = bf2[col];
        #pragma unroll
        for (int reg = 0; reg < 4; ++reg) {
            int r = row0 + w * 16 + (l >> 4) * 4 + reg;
            out[(size_t)r * 128 + col] = acc[cf][reg] + bv;
        }
    }
}

// ---------------------------------------------------------------------------
extern "C" void kernel_launch(void* const* d_in, const int* in_sizes, int n_in,
                              void* d_out, int out_size, void* d_ws, size_t ws_size,
                              hipStream_t stream)
{
    const float* x    = (const float*)d_in[0];
    const float* pos  = (const float*)d_in[1];
    const float* Wlt  = (const float*)d_in[2];
    const float* Wphi = (const float*)d_in[3];
    const float* bphi = (const float*)d_in[4];
    const float* Wc1  = (const float*)d_in[5];
    const float* bc1  = (const float*)d_in[6];
    const float* Wc2  = (const float*)d_in[7];
    const float* bc2  = (const float*)d_in[8];
    const float* lng  = (const float*)d_in[9];
    const float* lnb  = (const float*)d_in[10];
    const float* Wf1  = (const float*)d_in[11];
    const float* bf1  = (const float*)d_in[12];
    const float* Wf2  = (const float*)d_in[13];
    const float* bf2  = (const float*)d_in[14];

    float* ws = (float*)d_ws;
    ushort* x1b = (ushort*)ws;                     // [BN*128] bf16   8 MB
    float* S0   = ws + 2097152;                    // [1024]
    float* S1   = S0 + 1024;                       // [1024]
    float* T    = S1 + 1024;                       // [4096]
    float* PS   = T + 4096;                        // [512*256]       512 KB
    float* PT   = PS + 131072;                     // [512*512]       1 MB
    unsigned char* phi8 = (unsigned char*)(ws + 2496512);  // [BN*512] fp8  16 MB
    float* out  = (float*)d_out;

    k_fused1<<<dim3(BN / 64), 256, 0, stream>>>(x, Wlt, Wphi, bphi, pos, x1b, phi8, PS);
    k_finS<<<dim3(Bb), 256, 0, stream>>>(PS, S0, S1);
    k_reduceT<<<dim3(512), 256, 0, stream>>>(x1b, phi8, pos, S0, S1, PT);
    k_finT<<<dim3(16), 256, 0, stream>>>(PT, T);
    k_comb_ffn<<<dim3(BN / 64), 256, 0, stream>>>(x1b, phi8, pos, S0, S1, T,
                                                  Wc1, bc1, Wc2, bc2, lng, lnb,
                                                  Wf1, bf1, Wf2, bf2, out);
}